// Round 4
// baseline (176.661 us; speedup 1.0000x reference)
//
#include <hip/hip_runtime.h>

#define LOG100 4.605170185988091f
#define LOG2E  1.4426950408889634f

typedef _Float16 half8 __attribute__((ext_vector_type(8)));
typedef float f32x16 __attribute__((ext_vector_type(16)));

// ---- bias pack pre-kernel: biasP[h][kv/2][q] = fp16pair(bias[h][q][2kp], bias[h][q][2kp+1]) * LOG2E
__global__ __launch_bounds__(256) void bias_pack(const float* __restrict__ bias,
                                                 unsigned* __restrict__ biasP) {
  __shared__ float tile[32][33];
  const int head = blockIdx.z;
  const int m0 = blockIdx.x * 32;  // kv
  const int n0 = blockIdx.y * 32;  // q
  const float* src = bias + head * 65536;
  unsigned* dst = biasP + head * 32768;
  const int tx = threadIdx.x, ty = threadIdx.y;  // (32,8)
#pragma unroll
  for (int i = ty; i < 32; i += 8) tile[i][tx] = src[(n0 + i) * 256 + m0 + tx];
  __syncthreads();
#pragma unroll
  for (int j = ty; j < 16; j += 8) {
    const float lo = tile[tx][2 * j] * LOG2E;
    const float hi = tile[tx][2 * j + 1] * LOG2E;
    dst[(m0 / 2 + j) * 256 + n0 + tx] =
        __builtin_bit_cast(unsigned, __builtin_amdgcn_cvt_pkrtz(lo, hi));
  }
}

// ---- main attention kernel -------------------------------------------------
// block = (b,h); 512 threads = 8 waves; wave w owns q rows [w*32, w*32+32)
// kv processed in 2 halves of 128 -> LDS 32 KB -> target 4 blocks/CU
template <bool USE_BT>
__global__ __launch_bounds__(512, 4) void attn_kernel(
    const float* __restrict__ q, const float* __restrict__ k, const float* __restrict__ v,
    const float* __restrict__ logit_scale, const float* __restrict__ bias,
    const unsigned* __restrict__ biasP, float* __restrict__ out) {
  __shared__ __align__(16) char smem[32768];
  // Kn: [128][64] fp16, 128B rows, swizzle: byte ^= (row&15)<<3  (8B granule, 16 slots)
  // Vt: [64][128] fp16, 256B rows, swizzle: byte ^= (d&15)<<4    (16B granule, 16 slots)
  _Float16* Kn = (_Float16*)smem;
  _Float16* Vt = (_Float16*)(smem + 16384);

  const int tid = threadIdx.x;
  const int wave = tid >> 6;
  const int lane = tid & 63;
  const int l31 = lane & 31;
  const int hi = lane >> 5;  // 0/1
  const int head = blockIdx.x;
  const int b = blockIdx.y;

  const long base = ((long)(b * 8 + head)) * (256 * 64);
  const float* qp = q + base;
  const float* kp = k + base;
  const float* vp = v + base;

  // log2-domain scale: exp(min(ls,log100)) * log2(e)
  const float scale2 = __expf(fminf(logit_scale[head], LOG100)) * LOG2E;

  // ---- load + normalize Q into B-frags (registers) ----
  // B-frag (32x32x16): lane holds q-col = l31, d = dk*16 + hi*8 + j
  const int qrow = wave * 32 + l31;
  half8 qfrag[4];
  {
    float qf[4][8];
    float ssq = 0.f;
#pragma unroll
    for (int dk = 0; dk < 4; ++dk) {
      const float4 x0 = *(const float4*)(qp + qrow * 64 + dk * 16 + hi * 8);
      const float4 x1 = *(const float4*)(qp + qrow * 64 + dk * 16 + hi * 8 + 4);
      qf[dk][0] = x0.x; qf[dk][1] = x0.y; qf[dk][2] = x0.z; qf[dk][3] = x0.w;
      qf[dk][4] = x1.x; qf[dk][5] = x1.y; qf[dk][6] = x1.z; qf[dk][7] = x1.w;
      ssq += x0.x * x0.x + x0.y * x0.y + x0.z * x0.z + x0.w * x0.w;
      ssq += x1.x * x1.x + x1.y * x1.y + x1.z * x1.z + x1.w * x1.w;
    }
    ssq += __shfl_xor(ssq, 32);
    const float qinv = rsqrtf(fmaxf(ssq, 1e-24f));
#pragma unroll
    for (int dk = 0; dk < 4; ++dk)
#pragma unroll
      for (int j = 0; j < 8; ++j) qfrag[dk][j] = (_Float16)(qf[dk][j] * qinv);
  }

  f32x16 o0 = {};  // O^T d-tile 0 (d = 0..31): C layout col=q=l31, row=d
  f32x16 o1 = {};  // O^T d-tile 1 (d = 32..63)
  float m = -1.0e30f, lsum = 0.f;  // m in log2 domain

  const unsigned* bP = USE_BT ? (biasP + head * 32768 + qrow) : nullptr;  // + kp*256
  const float* bF = USE_BT ? nullptr : (bias + head * 65536 + qrow * 256 + 4 * hi);

  for (int h = 0; h < 2; ++h) {
    if (h) __syncthreads();  // previous half's readers done before overwrite

    // ---- stage K half: rows [h*128, h*128+128), L2-normalized fp16 ----
    {
      const int row_in = tid >> 4;  // 0..31
      const int seg = tid & 15;     // 16 segs * 4 floats = 64 d
#pragma unroll
      for (int it = 0; it < 4; ++it) {
        const int r = it * 32 + row_in;  // local 0..127
        const float4 a = *(const float4*)(kp + (h * 128 + r) * 64 + seg * 4);
        float ss = a.x * a.x + a.y * a.y + a.z * a.z + a.w * a.w;
        ss += __shfl_xor(ss, 1);
        ss += __shfl_xor(ss, 2);
        ss += __shfl_xor(ss, 4);
        ss += __shfl_xor(ss, 8);
        const float inv = rsqrtf(fmaxf(ss, 1e-24f));
        union { _Float16 hh[4]; uint2 u; } pk4;
        pk4.hh[0] = (_Float16)(a.x * inv);
        pk4.hh[1] = (_Float16)(a.y * inv);
        pk4.hh[2] = (_Float16)(a.z * inv);
        pk4.hh[3] = (_Float16)(a.w * inv);
        char* wp = (char*)Kn + r * 128 + ((seg * 8) ^ ((r & 15) << 3));
        *(uint2*)wp = pk4.u;
      }
    }

    // ---- stage V^T half: Vt[d][kv_local], in-register 4x4 transpose ----
    {
      const int r = lane >> 4;   // 0..3
      const int sx = lane & 15;
#pragma unroll
      for (int it = 0; it < 4; ++it) {
        const int kv0 = (wave * 4 + it) * 4;  // local 0..124
        float4 a = *(const float4*)(vp + (h * 128 + kv0 + r) * 64 + sx * 4);
        // transpose 4x4 across lanes {sx, sx+16, sx+32, sx+48}
        float e1 = (r & 1) ? a.x : a.y;
        float g1 = __shfl_xor(e1, 16);
        float e2 = (r & 1) ? a.z : a.w;
        float g2 = __shfl_xor(e2, 16);
        if (r & 1) { a.x = g1; a.z = g2; } else { a.y = g1; a.w = g2; }
        float e3 = (r & 2) ? a.x : a.z;
        float g3 = __shfl_xor(e3, 32);
        float e4 = (r & 2) ? a.y : a.w;
        float g4 = __shfl_xor(e4, 32);
        if (r & 2) { a.x = g3; a.y = g4; } else { a.z = g3; a.w = g4; }
        // lane holds V[kv0+0..3][d], d = 4*sx + r
        const int d = 4 * sx + r;
        union { _Float16 hh[4]; uint2 u; } pk4;
        pk4.hh[0] = (_Float16)a.x;
        pk4.hh[1] = (_Float16)a.y;
        pk4.hh[2] = (_Float16)a.z;
        pk4.hh[3] = (_Float16)a.w;
        char* wp = (char*)Vt + d * 256 + ((kv0 * 2) ^ ((d & 15) << 4));
        *(uint2*)wp = pk4.u;
      }
    }

    __syncthreads();

    // ---- 4 chunks of 32 kv ----
    for (int c = 0; c < 4; ++c) {
      // bias preload (L2-resident, independent of MFMAs)
      unsigned bw[8];
      float bvf[16];
      if (USE_BT) {
#pragma unroll
        for (int i = 0; i < 8; ++i) {
          const int kp_off = (i & 1) + 4 * (i >> 1) + 2 * hi;  // pair covers kv 2kp,2kp+1
          bw[i] = bP[(h * 64 + c * 16 + kp_off) * 256];
        }
      } else {
        const int kvg = h * 128 + c * 32;
#pragma unroll
        for (int reg = 0; reg < 16; ++reg) {
          const int kvr = (reg & 3) + 8 * (reg >> 2);
          bvf[reg] = bF[kvg + kvr] * LOG2E;
        }
      }

      // QK^T: S^T = K * Q^T.  A-frag: lane kv = c*32 + l31, d = dk*16 + hi*8 + j
      const int krow = c * 32 + l31;
      const char* kbase = (const char*)Kn + krow * 128;
      const int kmsk = (krow & 15) << 3;
      f32x16 s = {};
      __builtin_amdgcn_s_setprio(1);
#pragma unroll
      for (int dk = 0; dk < 4; ++dk) {
        union { uint2 u[2]; half8 hh; } kf;
        kf.u[0] = *(const uint2*)(kbase + ((dk * 32 + hi * 16) ^ kmsk));
        kf.u[1] = *(const uint2*)(kbase + ((dk * 32 + hi * 16 + 8) ^ kmsk));
        s = __builtin_amdgcn_mfma_f32_32x32x16_f16(kf.hh, qfrag[dk], s, 0, 0, 0);
      }
      __builtin_amdgcn_s_setprio(0);

      // scale + bias (log2 domain); s[reg]: kv = c*32 + (reg&3) + 8*(reg>>2) + 4*hi
      if (USE_BT) {
#pragma unroll
        for (int i = 0; i < 8; ++i) {
          const _Float16* hp = (const _Float16*)&bw[i];
          s[2 * i] = fmaf(s[2 * i], scale2, (float)hp[0]);
          s[2 * i + 1] = fmaf(s[2 * i + 1], scale2, (float)hp[1]);
        }
      } else {
#pragma unroll
        for (int reg = 0; reg < 16; ++reg) s[reg] = fmaf(s[reg], scale2, bvf[reg]);
      }

      // tree max + cross-half
      float m8[8];
#pragma unroll
      for (int i = 0; i < 8; ++i) m8[i] = fmaxf(s[2 * i], s[2 * i + 1]);
      float m4[4];
#pragma unroll
      for (int i = 0; i < 4; ++i) m4[i] = fmaxf(m8[2 * i], m8[2 * i + 1]);
      float mx = fmaxf(fmaxf(m4[0], m4[1]), fmaxf(m4[2], m4[3]));
      mx = fmaxf(mx, __shfl_xor(mx, 32));

      // defer-max: rescale only when running max grows by > 8 (log2)
      if (__any(mx > m + 8.0f)) {
        const float mnew = fmaxf(m, mx);
        const float corr = exp2f(m - mnew);
        lsum *= corr;
#pragma unroll
        for (int i = 0; i < 16; ++i) { o0[i] *= corr; o1[i] *= corr; }
        m = mnew;
      }

      // exp2 + tree psum
#pragma unroll
      for (int reg = 0; reg < 16; ++reg) s[reg] = exp2f(s[reg] - m);
      float a8[8];
#pragma unroll
      for (int i = 0; i < 8; ++i) a8[i] = s[2 * i] + s[2 * i + 1];
      float a4[4];
#pragma unroll
      for (int i = 0; i < 4; ++i) a4[i] = a8[2 * i] + a8[2 * i + 1];
      float psum = (a4[0] + a4[1]) + (a4[2] + a4[3]);
      psum += __shfl_xor(psum, 32);
      lsum += psum;

      // pack P f32->fp16 pairs; pk[i] = (p[2i], p[2i+1])
      unsigned pk[8];
#pragma unroll
      for (int i = 0; i < 8; ++i)
        pk[i] = __builtin_bit_cast(unsigned, __builtin_amdgcn_cvt_pkrtz(s[2 * i], s[2 * i + 1]));
      // exchange with lane^32: frag ks holds kv = c*32 + ks*16 + hi*8 + j
      const unsigned ra = __shfl_xor(hi ? pk[0] : pk[2], 32);
      const unsigned rb = __shfl_xor(hi ? pk[1] : pk[3], 32);
      const unsigned rc = __shfl_xor(hi ? pk[4] : pk[6], 32);
      const unsigned rd = __shfl_xor(hi ? pk[5] : pk[7], 32);
      union { unsigned u[4]; half8 hh; } f0, f1;
      f0.u[0] = hi ? ra : pk[0];
      f0.u[1] = hi ? rb : pk[1];
      f0.u[2] = hi ? pk[2] : ra;
      f0.u[3] = hi ? pk[3] : rb;
      f1.u[0] = hi ? rc : pk[4];
      f1.u[1] = hi ? rd : pk[5];
      f1.u[2] = hi ? pk[6] : rc;
      f1.u[3] = hi ? pk[7] : rd;

      // PV: O^T[d][q] += V^T[d][kv] * P^T[kv][q]
      {
        const int d = l31;  // d-tile 0
        const char* vbase = (const char*)Vt + d * 256;
        const int msk = (d & 15) << 4;
        const half8 vf0 = *(const half8*)(vbase + ((c * 64 + hi * 16) ^ msk));
        const half8 vf1 = *(const half8*)(vbase + ((c * 64 + 32 + hi * 16) ^ msk));
        __builtin_amdgcn_s_setprio(1);
        o0 = __builtin_amdgcn_mfma_f32_32x32x16_f16(vf0, f0.hh, o0, 0, 0, 0);
        o0 = __builtin_amdgcn_mfma_f32_32x32x16_f16(vf1, f1.hh, o0, 0, 0, 0);
        __builtin_amdgcn_s_setprio(0);
      }
      {
        const int d = 32 + l31;  // d-tile 1
        const char* vbase = (const char*)Vt + d * 256;
        const int msk = (d & 15) << 4;
        const half8 vf0 = *(const half8*)(vbase + ((c * 64 + hi * 16) ^ msk));
        const half8 vf1 = *(const half8*)(vbase + ((c * 64 + 32 + hi * 16) ^ msk));
        __builtin_amdgcn_s_setprio(1);
        o1 = __builtin_amdgcn_mfma_f32_32x32x16_f16(vf0, f0.hh, o1, 0, 0, 0);
        o1 = __builtin_amdgcn_mfma_f32_32x32x16_f16(vf1, f1.hh, o1, 0, 0, 0);
        __builtin_amdgcn_s_setprio(0);
      }
    }
  }

  __syncthreads();  // all waves done with Kn/Vt; reuse smem for epilogue

  // ---- epilogue: O^T -> per-wave fp16 LDS [32 q][64 d] (4 KB) -> coalesced stores
  // swizzle: byte ^= (q&15)<<3  (8B granule)
  char* ob = (char*)smem + wave * 4096;
  const float invl = 1.0f / lsum;
#pragma unroll
  for (int r = 0; r < 16; r += 2) {
    const int d0 = (r & 3) + 8 * (r >> 2) + 4 * hi;  // even; pair covers d0, d0+1
    const unsigned w0 =
        __builtin_bit_cast(unsigned, __builtin_amdgcn_cvt_pkrtz(o0[r] * invl, o0[r + 1] * invl));
    *(unsigned*)(ob + l31 * 128 + ((d0 * 2) ^ ((l31 & 15) << 3))) = w0;
    const unsigned w1 =
        __builtin_bit_cast(unsigned, __builtin_amdgcn_cvt_pkrtz(o1[r] * invl, o1[r + 1] * invl));
    *(unsigned*)(ob + l31 * 128 + (((d0 + 32) * 2) ^ ((l31 & 15) << 3))) = w1;
  }
  __asm__ __volatile__("s_waitcnt lgkmcnt(0)" ::: "memory");
  __builtin_amdgcn_sched_barrier(0);
  const int sx = lane & 15;
  const int rr = lane >> 4;
#pragma unroll
  for (int kq = 0; kq < 8; ++kq) {
    const int qq = kq * 4 + rr;  // 0..31
    union { uint2 u; _Float16 hh[4]; } rd4;
    rd4.u = *(const uint2*)(ob + qq * 128 + ((sx * 8) ^ ((qq & 15) << 3)));
    float4 val;
    val.x = (float)rd4.hh[0];
    val.y = (float)rd4.hh[1];
    val.z = (float)rd4.hh[2];
    val.w = (float)rd4.hh[3];
    *(float4*)(out + (((long)(b * 256 + wave * 32 + qq) * 8 + head) * 64 + 4 * sx)) = val;
  }
}

extern "C" void kernel_launch(void* const* d_in, const int* in_sizes, int n_in,
                              void* d_out, int out_size, void* d_ws, size_t ws_size,
                              hipStream_t stream) {
  (void)in_sizes; (void)n_in; (void)out_size;
  const float* q = (const float*)d_in[0];
  const float* k = (const float*)d_in[1];
  const float* v = (const float*)d_in[2];
  const float* ls = (const float*)d_in[3];
  const float* bias = (const float*)d_in[4];
  float* out = (float*)d_out;
  const size_t bpBytes = (size_t)8 * 128 * 256 * 4;  // 1 MB
  if (ws_size >= bpBytes) {
    unsigned* biasP = (unsigned*)d_ws;
    bias_pack<<<dim3(8, 8, 8), dim3(32, 8), 0, stream>>>(bias, biasP);
    attn_kernel<true><<<dim3(8, 256), dim3(512), 0, stream>>>(q, k, v, ls, bias, biasP, out);
  } else {
    attn_kernel<false><<<dim3(8, 256), dim3(512), 0, stream>>>(q, k, v, ls, bias, nullptr, out);
  }
}

// Round 5
// 146.425 us; speedup vs baseline: 1.2065x; 1.2065x over previous
//
#include <hip/hip_runtime.h>

#define LOG100 4.605170185988091f
#define LOG2E  1.4426950408889634f

typedef _Float16 half8 __attribute__((ext_vector_type(8)));
typedef float f32x16 __attribute__((ext_vector_type(16)));

// ---- bias pack pre-kernel: biasP[h][kv/2][q] = fp16pair(bias[h][q][2kp], bias[h][q][2kp+1]) * LOG2E
__global__ __launch_bounds__(256) void bias_pack(const float* __restrict__ bias,
                                                 unsigned* __restrict__ biasP) {
  __shared__ float tile[32][33];
  const int head = blockIdx.z;
  const int m0 = blockIdx.x * 32;  // kv
  const int n0 = blockIdx.y * 32;  // q
  const float* src = bias + head * 65536;
  unsigned* dst = biasP + head * 32768;
  const int tx = threadIdx.x, ty = threadIdx.y;  // (32,8)
#pragma unroll
  for (int i = ty; i < 32; i += 8) tile[i][tx] = src[(n0 + i) * 256 + m0 + tx];
  __syncthreads();
#pragma unroll
  for (int j = ty; j < 16; j += 8) {
    const float lo = tile[tx][2 * j] * LOG2E;
    const float hi = tile[tx][2 * j + 1] * LOG2E;
    dst[(m0 / 2 + j) * 256 + n0 + tx] =
        __builtin_bit_cast(unsigned, __builtin_amdgcn_cvt_pkrtz(lo, hi));
  }
}

// ---- main attention kernel -------------------------------------------------
// block = (b,h); 512 threads = 8 waves; wave w owns q rows [w*32, w*32+32)
// Full K,V staged once (64 KB LDS); kv loop = 8 chunks of 32, 2-deep pipelined.
template <bool USE_BT>
__global__ __launch_bounds__(512, 4) void attn_kernel(
    const float* __restrict__ q, const float* __restrict__ k, const float* __restrict__ v,
    const float* __restrict__ logit_scale, const float* __restrict__ bias,
    const unsigned* __restrict__ biasP, float* __restrict__ out) {
  __shared__ __align__(16) char smem[65536];
  // Kn: [256][64] fp16, 128B rows, swizzle: byte ^= (row&7)<<4  (16B granule, 8 slots)
  // Vt: [64][256] fp16, 512B rows, swizzle: byte ^= (d&31)<<4   (16B granule, 32 slots)
  _Float16* Kn = (_Float16*)smem;
  _Float16* Vt = (_Float16*)(smem + 32768);

  const int tid = threadIdx.x;
  const int wave = tid >> 6;
  const int lane = tid & 63;
  const int l31 = lane & 31;
  const int hi = lane >> 5;  // 0/1
  const int head = blockIdx.x;
  const int b = blockIdx.y;

  const long base = ((long)(b * 8 + head)) * (256 * 64);
  const float* qp = q + base;
  const float* kp = k + base;
  const float* vp = v + base;

  // log2-domain scale: exp(min(ls,log100)) * log2(e)
  const float scale2 = __expf(fminf(logit_scale[head], LOG100)) * LOG2E;

  // ---- load + normalize Q into B-frags (registers) ----
  // B-frag (32x32x16): lane holds q-col = l31, d = dk*16 + hi*8 + j
  const int qrow = wave * 32 + l31;
  half8 qfrag[4];
  {
    float qf[4][8];
    float ssq = 0.f;
#pragma unroll
    for (int dk = 0; dk < 4; ++dk) {
      const float4 x0 = *(const float4*)(qp + qrow * 64 + dk * 16 + hi * 8);
      const float4 x1 = *(const float4*)(qp + qrow * 64 + dk * 16 + hi * 8 + 4);
      qf[dk][0] = x0.x; qf[dk][1] = x0.y; qf[dk][2] = x0.z; qf[dk][3] = x0.w;
      qf[dk][4] = x1.x; qf[dk][5] = x1.y; qf[dk][6] = x1.z; qf[dk][7] = x1.w;
      ssq += x0.x * x0.x + x0.y * x0.y + x0.z * x0.z + x0.w * x0.w;
      ssq += x1.x * x1.x + x1.y * x1.y + x1.z * x1.z + x1.w * x1.w;
    }
    ssq += __shfl_xor(ssq, 32);
    const float qinv = rsqrtf(fmaxf(ssq, 1e-24f));
#pragma unroll
    for (int dk = 0; dk < 4; ++dk)
#pragma unroll
      for (int j = 0; j < 8; ++j) qfrag[dk][j] = (_Float16)(qf[dk][j] * qinv);
  }

  // ---- stage K, L2-normalized, fp16, swizzled ----
  {
    const int row_in = tid >> 4;  // 0..31
    const int seg = tid & 15;     // 16 segs * 4 floats = 64 d
#pragma unroll
    for (int it = 0; it < 8; ++it) {
      const int row = it * 32 + row_in;
      const float4 a = *(const float4*)(kp + row * 64 + seg * 4);
      float ss = a.x * a.x + a.y * a.y + a.z * a.z + a.w * a.w;
      ss += __shfl_xor(ss, 1);
      ss += __shfl_xor(ss, 2);
      ss += __shfl_xor(ss, 4);
      ss += __shfl_xor(ss, 8);
      const float inv = rsqrtf(fmaxf(ss, 1e-24f));
      union { _Float16 hh[4]; uint2 u; } pk4;
      pk4.hh[0] = (_Float16)(a.x * inv);
      pk4.hh[1] = (_Float16)(a.y * inv);
      pk4.hh[2] = (_Float16)(a.z * inv);
      pk4.hh[3] = (_Float16)(a.w * inv);
      char* wp = (char*)Kn + row * 128 + ((seg * 8) ^ ((row & 7) << 4));
      *(uint2*)wp = pk4.u;
    }
  }

  // ---- stage V transposed: Vt[d][kv], via in-register 4x4 transpose ----
  {
    const int r = lane >> 4;   // 0..3
    const int sx = lane & 15;
#pragma unroll
    for (int it = 0; it < 8; ++it) {
      const int kv0 = (wave * 8 + it) * 4;  // 0..252
      float4 a = *(const float4*)(vp + (kv0 + r) * 64 + sx * 4);
      // transpose 4x4 across lanes {sx, sx+16, sx+32, sx+48}
      float e1 = (r & 1) ? a.x : a.y;
      float g1 = __shfl_xor(e1, 16);
      float e2 = (r & 1) ? a.z : a.w;
      float g2 = __shfl_xor(e2, 16);
      if (r & 1) { a.x = g1; a.z = g2; } else { a.y = g1; a.w = g2; }
      float e3 = (r & 2) ? a.x : a.z;
      float g3 = __shfl_xor(e3, 32);
      float e4 = (r & 2) ? a.y : a.w;
      float g4 = __shfl_xor(e4, 32);
      if (r & 2) { a.x = g3; a.y = g4; } else { a.z = g3; a.w = g4; }
      // lane holds V[kv0+0..3][d], d = 4*sx + r
      const int d = 4 * sx + r;
      union { _Float16 hh[4]; uint2 u; } pk4;
      pk4.hh[0] = (_Float16)a.x;
      pk4.hh[1] = (_Float16)a.y;
      pk4.hh[2] = (_Float16)a.z;
      pk4.hh[3] = (_Float16)a.w;
      char* wp = (char*)Vt + d * 512 + ((kv0 * 2) ^ ((d & 31) << 4));
      *(uint2*)wp = pk4.u;
    }
  }

  __syncthreads();

  // ---- kv loop state ----
  f32x16 o0 = {};  // O^T d-tile 0 (d = 0..31): C layout col=q=l31, row=d
  f32x16 o1 = {};  // O^T d-tile 1 (d = 32..63)
  float m = -1.0e30f, lsum = 0.f;  // log2 domain

  const unsigned* bP = USE_BT ? (biasP + head * 32768 + qrow) : nullptr;  // + kp*256
  const float* bF = USE_BT ? nullptr : (bias + head * 65536 + qrow * 256 + 4 * hi);

  // bias loader for chunk c (8 fp16-pairs covering 16 kv values of this lane)
  auto LOADB = [&](int c, unsigned bw[8]) {
    if (USE_BT) {
#pragma unroll
      for (int i = 0; i < 8; ++i) {
        const int kp_off = (i & 1) + 4 * (i >> 1) + 2 * hi;
        bw[i] = bP[(c * 16 + kp_off) * 256];
      }
    } else {
#pragma unroll
      for (int i = 0; i < 8; ++i) {
        const int kvr0 = 2 * ((i & 1) + 4 * (i >> 1) + 2 * hi);
        const float lo = bF[c * 32 + kvr0 - 4 * hi + ((kvr0 & 7) >= 4 ? 0 : 0)] * LOG2E;
        // non-BT fallback: load the two scalars directly (kv = c*32 + kvr)
        const float l0 = bF[c * 32 + ((2 * i) & 3) + 8 * ((2 * i) >> 2)] * LOG2E;
        const float l1 = bF[c * 32 + ((2 * i + 1) & 3) + 8 * ((2 * i + 1) >> 2)] * LOG2E;
        bw[i] = __builtin_bit_cast(unsigned, __builtin_amdgcn_cvt_pkrtz(l0, l1));
        (void)lo; (void)kvr0;
      }
    }
  };

  // QK^T for chunk c: S^T tile, s[reg] = S^T[kv = c*32 + (reg&3) + 8*(reg>>2) + 4*hi][q = qrow]
  auto QKT = [&](int c) -> f32x16 {
    const int krow = c * 32 + l31;
    const char* kbase = (const char*)Kn + krow * 128;
    const int kmsk = (krow & 7) << 4;
    f32x16 s = {};
#pragma unroll
    for (int dk = 0; dk < 4; ++dk) {
      const half8 kf = *(const half8*)(kbase + ((dk * 32 + hi * 16) ^ kmsk));
      s = __builtin_amdgcn_mfma_f32_32x32x16_f16(kf, qfrag[dk], s, 0, 0, 0);
    }
    return s;
  };

  // softmax + PV for chunk c
  auto SOFTPV = [&](f32x16 s, int c, const unsigned bw[8]) {
    // scale + bias (log2 domain)
#pragma unroll
    for (int i = 0; i < 8; ++i) {
      const _Float16* hp = (const _Float16*)&bw[i];
      s[2 * i] = fmaf(s[2 * i], scale2, (float)hp[0]);
      s[2 * i + 1] = fmaf(s[2 * i + 1], scale2, (float)hp[1]);
    }
    // tree max + cross-half
    float m8[8];
#pragma unroll
    for (int i = 0; i < 8; ++i) m8[i] = fmaxf(s[2 * i], s[2 * i + 1]);
    float m4[4];
#pragma unroll
    for (int i = 0; i < 4; ++i) m4[i] = fmaxf(m8[2 * i], m8[2 * i + 1]);
    float mx = fmaxf(fmaxf(m4[0], m4[1]), fmaxf(m4[2], m4[3]));
    mx = fmaxf(mx, __shfl_xor(mx, 32));
    // defer-max: rescale only when running max grows by > 8 (log2)
    if (__any(mx > m + 8.0f)) {
      const float mnew = fmaxf(m, mx);
      const float corr = exp2f(m - mnew);
      lsum *= corr;
#pragma unroll
      for (int i = 0; i < 16; ++i) { o0[i] *= corr; o1[i] *= corr; }
      m = mnew;
    }
    // exp2 + tree psum
#pragma unroll
    for (int reg = 0; reg < 16; ++reg) s[reg] = exp2f(s[reg] - m);
    float a8[8];
#pragma unroll
    for (int i = 0; i < 8; ++i) a8[i] = s[2 * i] + s[2 * i + 1];
    float a4[4];
#pragma unroll
    for (int i = 0; i < 4; ++i) a4[i] = a8[2 * i] + a8[2 * i + 1];
    float psum = (a4[0] + a4[1]) + (a4[2] + a4[3]);
    psum += __shfl_xor(psum, 32);
    lsum += psum;
    // pack P f32->fp16 pairs
    unsigned pk[8];
#pragma unroll
    for (int i = 0; i < 8; ++i)
      pk[i] = __builtin_bit_cast(unsigned, __builtin_amdgcn_cvt_pkrtz(s[2 * i], s[2 * i + 1]));
    // exchange with lane^32: frag ks holds kv = c*32 + ks*16 + hi*8 + j
    const unsigned ra = __shfl_xor(hi ? pk[0] : pk[2], 32);
    const unsigned rb = __shfl_xor(hi ? pk[1] : pk[3], 32);
    const unsigned rc = __shfl_xor(hi ? pk[4] : pk[6], 32);
    const unsigned rd = __shfl_xor(hi ? pk[5] : pk[7], 32);
    union { unsigned u[4]; half8 hh; } f0, f1;
    f0.u[0] = hi ? ra : pk[0];
    f0.u[1] = hi ? rb : pk[1];
    f0.u[2] = hi ? pk[2] : ra;
    f0.u[3] = hi ? pk[3] : rb;
    f1.u[0] = hi ? rc : pk[4];
    f1.u[1] = hi ? rd : pk[5];
    f1.u[2] = hi ? pk[6] : rc;
    f1.u[3] = hi ? pk[7] : rd;
    // PV: O^T[d][q] += V^T[d][kv] * P^T[kv][q]
    {
      const int d = l31;  // d-tile 0
      const char* vbase = (const char*)Vt + d * 512;
      const int msk = (d & 31) << 4;
      const half8 vf0 = *(const half8*)(vbase + ((c * 64 + hi * 16) ^ msk));
      const half8 vf1 = *(const half8*)(vbase + ((c * 64 + 32 + hi * 16) ^ msk));
      o0 = __builtin_amdgcn_mfma_f32_32x32x16_f16(vf0, f0.hh, o0, 0, 0, 0);
      o0 = __builtin_amdgcn_mfma_f32_32x32x16_f16(vf1, f1.hh, o0, 0, 0, 0);
    }
    {
      const int d = 32 + l31;  // d-tile 1
      const char* vbase = (const char*)Vt + d * 512;
      const int msk = (d & 31) << 4;
      const half8 vf0 = *(const half8*)(vbase + ((c * 64 + hi * 16) ^ msk));
      const half8 vf1 = *(const half8*)(vbase + ((c * 64 + 32 + hi * 16) ^ msk));
      o1 = __builtin_amdgcn_mfma_f32_32x32x16_f16(vf0, f0.hh, o1, 0, 0, 0);
      o1 = __builtin_amdgcn_mfma_f32_32x32x16_f16(vf1, f1.hh, o1, 0, 0, 0);
    }
  };

  // ---- 2-deep pipelined chunk loop (fully unrolled; named A/B state, rule #20) ----
  unsigned bwA[8], bwB[8];
  LOADB(0, bwA);
  f32x16 sA = QKT(0);
#pragma unroll
  for (int cc = 0; cc < 4; ++cc) {
    LOADB(2 * cc + 1, bwB);
    f32x16 sB = QKT(2 * cc + 1);
    SOFTPV(sA, 2 * cc, bwA);
    if (cc < 3) {
      LOADB(2 * cc + 2, bwA);
      sA = QKT(2 * cc + 2);
    }
    SOFTPV(sB, 2 * cc + 1, bwB);
  }

  __syncthreads();  // all waves done with Kn/Vt; reuse smem for epilogue

  // ---- epilogue: O^T -> per-wave fp16 LDS [32 q][64 d] (4 KB) -> coalesced stores
  // swizzle: byte ^= (q&15)<<3  (8B granule)
  char* ob = (char*)smem + wave * 4096;
  const float invl = 1.0f / lsum;
#pragma unroll
  for (int r = 0; r < 16; r += 2) {
    const int d0 = (r & 3) + 8 * (r >> 2) + 4 * hi;  // even; pair covers d0, d0+1
    const unsigned w0 =
        __builtin_bit_cast(unsigned, __builtin_amdgcn_cvt_pkrtz(o0[r] * invl, o0[r + 1] * invl));
    *(unsigned*)(ob + l31 * 128 + ((d0 * 2) ^ ((l31 & 15) << 3))) = w0;
    const unsigned w1 =
        __builtin_bit_cast(unsigned, __builtin_amdgcn_cvt_pkrtz(o1[r] * invl, o1[r + 1] * invl));
    *(unsigned*)(ob + l31 * 128 + (((d0 + 32) * 2) ^ ((l31 & 15) << 3))) = w1;
  }
  __asm__ __volatile__("s_waitcnt lgkmcnt(0)" ::: "memory");
  __builtin_amdgcn_sched_barrier(0);
  const int sx = lane & 15;
  const int rr = lane >> 4;
#pragma unroll
  for (int kq = 0; kq < 8; ++kq) {
    const int qq = kq * 4 + rr;  // 0..31
    union { uint2 u; _Float16 hh[4]; } rd4;
    rd4.u = *(const uint2*)(ob + qq * 128 + ((sx * 8) ^ ((qq & 15) << 3)));
    float4 val;
    val.x = (float)rd4.hh[0];
    val.y = (float)rd4.hh[1];
    val.z = (float)rd4.hh[2];
    val.w = (float)rd4.hh[3];
    *(float4*)(out + (((long)(b * 256 + wave * 32 + qq) * 8 + head) * 64 + 4 * sx)) = val;
  }
}

extern "C" void kernel_launch(void* const* d_in, const int* in_sizes, int n_in,
                              void* d_out, int out_size, void* d_ws, size_t ws_size,
                              hipStream_t stream) {
  (void)in_sizes; (void)n_in; (void)out_size;
  const float* q = (const float*)d_in[0];
  const float* k = (const float*)d_in[1];
  const float* v = (const float*)d_in[2];
  const float* ls = (const float*)d_in[3];
  const float* bias = (const float*)d_in[4];
  float* out = (float*)d_out;
  const size_t bpBytes = (size_t)8 * 128 * 256 * 4;  // 1 MB
  if (ws_size >= bpBytes) {
    unsigned* biasP = (unsigned*)d_ws;
    bias_pack<<<dim3(8, 8, 8), dim3(32, 8), 0, stream>>>(bias, biasP);
    attn_kernel<true><<<dim3(8, 256), dim3(512), 0, stream>>>(q, k, v, ls, bias, biasP, out);
  } else {
    attn_kernel<false><<<dim3(8, 256), dim3(512), 0, stream>>>(q, k, v, ls, bias, nullptr, out);
  }
}